// Round 1
// 8443.907 us; speedup vs baseline: 2.6456x; 2.6456x over previous
//
// R1: restructure — attention hoisted out of the recurrence.
// Phase 1 (sequential): 256x fused gates-GEMM + LSTM-cell kernel (1 launch/step).
// Phase 2 (parallel over t): target GEMM, fused energy+softmax, context GEMM
// (bf16 MFMA vs transposed ctx), h_tilde GEMM. ~270 dispatches vs ~1800.
#include <hip/hip_runtime.h>
#include <stdint.h>

#define BB 64
#define TT 256
#define SS 256
#define HH 1024
#define II 1024
#define H4 4096
#define H2 2048

static const size_t BTH = (size_t)BB * TT * HH;   // 16777216
static const size_t BTS = (size_t)BB * TT * SS;   // 4194304

typedef unsigned short u16;
typedef __attribute__((ext_vector_type(8))) short short8;
typedef __attribute__((ext_vector_type(4))) float f32x4;

__device__ inline u16 f2bf(float x) {
    union { float f; uint32_t u; } v; v.f = x;
    uint32_t r = (v.u + 0x7FFFu + ((v.u >> 16) & 1u)) >> 16;
    return (u16)r;
}
__device__ inline float bf2f(u16 b) {
    union { float f; uint32_t u; } v; v.u = ((uint32_t)b) << 16;
    return v.f;
}
__device__ inline float fexp2(float x) {
#if __has_builtin(__builtin_amdgcn_exp2f)
    return __builtin_amdgcn_exp2f(x);
#else
    return exp2f(x);
#endif
}
__device__ inline float fast_tanh(float x) {
    x = fminf(fmaxf(x, -15.f), 15.f);
    float t = fexp2(2.885390081777927f * x);   // e^{2x}
    return (t - 1.f) / (t + 1.f);
}
__device__ inline float sigmoidf_(float x) {
    x = fminf(fmaxf(x, -30.f), 30.f);
    float t = fexp2(-1.4426950408889634f * x); // e^{-x}
    return 1.f / (1.f + t);
}

// 16x16 tile K-loop: A rows (m=lane&15), B rows = W[n][k] row-major, both k-contig.
__device__ inline f32x4 mfma_acc(const u16* __restrict__ a, const u16* __restrict__ b,
                                 int K, f32x4 acc) {
#pragma unroll 4
    for (int k = 0; k < K; k += 32) {
        short8 av = *(const short8*)(a + k);
        short8 bv = *(const short8*)(b + k);
        acc = __builtin_amdgcn_mfma_f32_16x16x32_bf16(av, bv, acc, 0, 0, 0);
    }
    return acc;
}

__global__ __launch_bounds__(256) void k_f2bf(const float* __restrict__ src,
                                              u16* __restrict__ dst, int n) {
    int i = blockIdx.x * 256 + threadIdx.x;
    if (i < n) dst[i] = f2bf(src[i]);
}

// ctxT[b][h][s] = bf16(ctx[b][s][h])  (one-time transpose for context GEMM B-operand)
__global__ __launch_bounds__(256) void k_ctxT(const float* __restrict__ ctx,
                                              u16* __restrict__ ctxT) {
    __shared__ u16 tile[32][33];
    int blk = blockIdx.x;
    int b = blk >> 8;
    int rem = blk & 255;
    int s0 = (rem >> 5) * 32, h0 = (rem & 31) * 32;
    int tx = threadIdx.x & 31, ty = threadIdx.x >> 5;   // 32 x 8
#pragma unroll
    for (int i = 0; i < 4; ++i) {
        int sl = ty + 8 * i;
        tile[sl][tx] = f2bf(ctx[((size_t)b * SS + s0 + sl) * HH + h0 + tx]);
    }
    __syncthreads();
#pragma unroll
    for (int i = 0; i < 4; ++i) {
        int hl = ty + 8 * i;
        ctxT[((size_t)b * HH + h0 + hl) * SS + s0 + tx] = tile[tx][hl];
    }
}

// xg[t][b][n] = input[b,t,:] @ W_in.T + b_in   (M = T*B, m = t*64+b), bf16 out
__global__ __launch_bounds__(256) void k_xg_gemm(const u16* __restrict__ inbf,
                                                 const u16* __restrict__ winbf,
                                                 const float* __restrict__ b_in,
                                                 u16* __restrict__ xg) {
    int lane = threadIdx.x & 63, wave = threadIdx.x >> 6;
    int tile = blockIdx.x * 4 + wave;     // 262144 tiles
    int mt = tile >> 8, nt = tile & 255;  // tiles_n = 256
    int kq = (lane >> 4) * 8;
    int arow = mt * 16 + (lane & 15);
    int t = arow >> 6, b = arow & 63;
    const u16* ap = inbf + ((size_t)(b * TT + t)) * II + kq;
    const u16* bp = winbf + ((size_t)(nt * 16 + (lane & 15))) * II + kq;
    f32x4 acc = mfma_acc(ap, bp, II, f32x4{0.f, 0.f, 0.f, 0.f});
    int n = nt * 16 + (lane & 15);
    float bias = b_in[n];
    int mbase = mt * 16 + (lane >> 4) * 4;
#pragma unroll
    for (int r = 0; r < 4; ++r)
        xg[(size_t)(mbase + r) * H4 + n] = f2bf(acc[r] + bias);
}

// source[b,s,:] = ctx[b,s,:] @ Wa_c.T + ba_c   (M = B*S), bf16 out
__global__ __launch_bounds__(256) void k_src_gemm(const u16* __restrict__ ctxbf,
                                                  const u16* __restrict__ wacbf,
                                                  const float* __restrict__ ba_c,
                                                  u16* __restrict__ srcbf) {
    int lane = threadIdx.x & 63, wave = threadIdx.x >> 6;
    int tile = blockIdx.x * 4 + wave;    // 65536 tiles
    int mt = tile >> 6, nt = tile & 63;
    int kq = (lane >> 4) * 8;
    const u16* ap = ctxbf + ((size_t)(mt * 16 + (lane & 15))) * HH + kq;
    const u16* bp = wacbf + ((size_t)(nt * 16 + (lane & 15))) * HH + kq;
    f32x4 acc = mfma_acc(ap, bp, HH, f32x4{0.f, 0.f, 0.f, 0.f});
    int n = nt * 16 + (lane & 15);
    float bias = ba_c[n];
    int mbase = mt * 16 + (lane >> 4) * 4;
#pragma unroll
    for (int r = 0; r < 4; ++r)
        srcbf[(size_t)(mbase + r) * HH + n] = f2bf(acc[r] + bias);
}

__global__ __launch_bounds__(256) void k_init(const float* __restrict__ hx0,
                                              const float* __restrict__ cx0,
                                              float* __restrict__ cell,
                                              u16* __restrict__ h0bf) {
    int i = blockIdx.x * 256 + threadIdx.x;  // 65536 = B*H
    cell[i] = cx0[i];
    h0bf[i] = f2bf(hx0[i]);
}

// Fused per-step: gates = hy_prev@W_hid.T (+b_hid +xg) -> LSTM cell -> hy.
// grid 256 blocks (mt 4 x ht 64) x 512 threads; 8 waves = 8 K-chunks of 128.
// Each wave computes all 4 gate quadrants for its (b-tile, h-tile, K-chunk);
// fp32 partials reduced via LDS, then 256 threads do the cell elementwise.
__global__ __launch_bounds__(512) void k_step(const u16* __restrict__ hprev,
                                              const u16* __restrict__ whidbf,
                                              const u16* __restrict__ xg_t,
                                              const float* __restrict__ b_hid,
                                              float* __restrict__ cell,
                                              float* __restrict__ outh_t,
                                              u16* __restrict__ hbf_t) {
    __shared__ float part[8][4][16][16];   // [ks][gate][m][n] 32 KB
    int tid = threadIdx.x;
    int lane = tid & 63, ks = tid >> 6;
    int mt = blockIdx.x >> 6, ht = blockIdx.x & 63;
    int kq = ks * 128 + ((lane >> 4) << 3);
    const u16* ap = hprev + (size_t)(mt * 16 + (lane & 15)) * HH + kq;
    int nrow = ht * 16 + (lane & 15);
    const u16* bp0 = whidbf + (size_t)nrow * HH + kq;
    const u16* bp1 = bp0 + (size_t)HH * HH;
    const u16* bp2 = bp1 + (size_t)HH * HH;
    const u16* bp3 = bp2 + (size_t)HH * HH;
    f32x4 a0 = {0.f,0.f,0.f,0.f}, a1 = a0, a2 = a0, a3 = a0;
#pragma unroll
    for (int k = 0; k < 128; k += 32) {
        short8 av = *(const short8*)(ap + k);
        a0 = __builtin_amdgcn_mfma_f32_16x16x32_bf16(av, *(const short8*)(bp0 + k), a0, 0, 0, 0);
        a1 = __builtin_amdgcn_mfma_f32_16x16x32_bf16(av, *(const short8*)(bp1 + k), a1, 0, 0, 0);
        a2 = __builtin_amdgcn_mfma_f32_16x16x32_bf16(av, *(const short8*)(bp2 + k), a2, 0, 0, 0);
        a3 = __builtin_amdgcn_mfma_f32_16x16x32_bf16(av, *(const short8*)(bp3 + k), a3, 0, 0, 0);
    }
    int ml = (lane >> 4) << 2, nl = lane & 15;
#pragma unroll
    for (int r = 0; r < 4; ++r) {
        part[ks][0][ml + r][nl] = a0[r];
        part[ks][1][ml + r][nl] = a1[r];
        part[ks][2][ml + r][nl] = a2[r];
        part[ks][3][ml + r][nl] = a3[r];
    }
    __syncthreads();
    if (tid < 256) {
        int m = tid >> 4, hl = tid & 15;
        int b = mt * 16 + m, h = ht * 16 + hl;
        float g[4];
#pragma unroll
        for (int gg = 0; gg < 4; ++gg) {
            float s = b_hid[gg * HH + h] + bf2f(xg_t[(size_t)b * H4 + gg * HH + h]);
#pragma unroll
            for (int kk = 0; kk < 8; ++kk) s += part[kk][gg][m][hl];
            g[gg] = s;
        }
        float ig = sigmoidf_(g[0]), fg = sigmoidf_(g[1]);
        float gv = fast_tanh(g[2]), og = sigmoidf_(g[3]);
        int idx = b * HH + h;
        float cy = fg * cell[idx] + ig * gv;
        float hy = og * fast_tanh(cy);
        cell[idx] = cy;
        outh_t[(size_t)b * TT * HH + h] = hy;   // h_out[b,t,:]
        hbf_t[idx] = f2bf(hy);                  // hbf[t][b][:]
    }
}

// target[m,n] = hbf[m,:] @ Wa_in.T   (M = T*B = 16384, m = t*64+b), fp32 out
__global__ __launch_bounds__(256) void k_target_big(const u16* __restrict__ hbf,
                                                    const u16* __restrict__ wainbf,
                                                    float* __restrict__ target) {
    int lane = threadIdx.x & 63, wave = threadIdx.x >> 6;
    int tile = blockIdx.x * 4 + wave;    // 65536 tiles
    int mt = tile >> 6, nt = tile & 63;
    int kq = (lane >> 4) * 8;
    const u16* ap = hbf + (size_t)(mt * 16 + (lane & 15)) * HH + kq;
    const u16* bp = wainbf + (size_t)(nt * 16 + (lane & 15)) * HH + kq;
    f32x4 acc = mfma_acc(ap, bp, HH, f32x4{0.f, 0.f, 0.f, 0.f});
    int n = nt * 16 + (lane & 15);
    int mbase = mt * 16 + (lane >> 4) * 4;
#pragma unroll
    for (int r = 0; r < 4; ++r)
        target[(size_t)(mbase + r) * HH + n] = acc[r];
}

// Fused energy + softmax for all t.  grid = B * T/16 blocks, 4 waves x 4 t each.
// Per lane: 16-h slice; per s: load src row slice once, accumulate 4 t dots;
// butterfly-reduce; keep e in regs (lane owns s where s&63==lane); softmax in-reg.
__global__ __launch_bounds__(256) void k_attn(const float* __restrict__ target,
                                              const u16* __restrict__ srcbf,
                                              const float* __restrict__ wav,
                                              float* __restrict__ out_attn,
                                              u16* __restrict__ abf) {
    int lane = threadIdx.x & 63, wave = threadIdx.x >> 6;
    int b = blockIdx.x >> 4, tg = blockIdx.x & 15;
    int t0 = tg * 16 + wave * 4;
    int hbase = lane * 16;
    float wv[16], tgt[4][16];
#pragma unroll
    for (int j = 0; j < 16; ++j) wv[j] = wav[hbase + j];
#pragma unroll
    for (int tt = 0; tt < 4; ++tt) {
        const float* tp = target + (size_t)((t0 + tt) * 64 + b) * HH + hbase;
#pragma unroll
        for (int j = 0; j < 16; ++j) tgt[tt][j] = tp[j];
    }
    float e0[4], e1[4], e2[4], e3[4];
#pragma unroll
    for (int so = 0; so < 4; ++so) {
        e0[so] = 0.f; e1[so] = 0.f; e2[so] = 0.f; e3[so] = 0.f;
        for (int si = 0; si < 64; ++si) {
            int s = so * 64 + si;
            const u16* sp = srcbf + ((size_t)(b * SS + s)) * HH + hbase;
            short8 v0 = *(const short8*)sp;
            short8 v1 = *(const short8*)(sp + 8);
            float sv[16];
#pragma unroll
            for (int j = 0; j < 8; ++j) {
                sv[j] = bf2f((u16)v0[j]);
                sv[8 + j] = bf2f((u16)v1[j]);
            }
            float a0 = 0.f, a1 = 0.f, a2 = 0.f, a3 = 0.f;
#pragma unroll
            for (int j = 0; j < 16; ++j) {
                float s0 = sv[j];
                a0 += fast_tanh(tgt[0][j] + s0) * wv[j];
                a1 += fast_tanh(tgt[1][j] + s0) * wv[j];
                a2 += fast_tanh(tgt[2][j] + s0) * wv[j];
                a3 += fast_tanh(tgt[3][j] + s0) * wv[j];
            }
#pragma unroll
            for (int m = 32; m >= 1; m >>= 1) {
                a0 += __shfl_xor(a0, m);
                a1 += __shfl_xor(a1, m);
                a2 += __shfl_xor(a2, m);
                a3 += __shfl_xor(a3, m);
            }
            bool keep = (lane == si);
            e0[so] = keep ? a0 : e0[so];
            e1[so] = keep ? a1 : e1[so];
            e2[so] = keep ? a2 : e2[so];
            e3[so] = keep ? a3 : e3[so];
        }
    }
    // softmax per t (row of 256 s spread as 4 regs x 64 lanes)
#pragma unroll
    for (int tt = 0; tt < 4; ++tt) {
        float r0, r1, r2, r3;
        if (tt == 0) { r0 = e0[0]; r1 = e0[1]; r2 = e0[2]; r3 = e0[3]; }
        else if (tt == 1) { r0 = e1[0]; r1 = e1[1]; r2 = e1[2]; r3 = e1[3]; }
        else if (tt == 2) { r0 = e2[0]; r1 = e2[1]; r2 = e2[2]; r3 = e2[3]; }
        else { r0 = e3[0]; r1 = e3[1]; r2 = e3[2]; r3 = e3[3]; }
        float mx = fmaxf(fmaxf(r0, r1), fmaxf(r2, r3));
#pragma unroll
        for (int m = 32; m >= 1; m >>= 1) mx = fmaxf(mx, __shfl_xor(mx, m));
        const float L2E = 1.4426950408889634f;
        float p0 = fexp2((r0 - mx) * L2E);
        float p1 = fexp2((r1 - mx) * L2E);
        float p2 = fexp2((r2 - mx) * L2E);
        float p3 = fexp2((r3 - mx) * L2E);
        float sm = p0 + p1 + p2 + p3;
#pragma unroll
        for (int m = 32; m >= 1; m >>= 1) sm += __shfl_xor(sm, m);
        float inv = 1.f / sm;
        size_t obase = (size_t)(b * TT + t0 + tt) * SS;
        float a;
        a = p0 * inv; out_attn[obase + lane] = a;       abf[obase + lane] = f2bf(a);
        a = p1 * inv; out_attn[obase + 64 + lane] = a;  abf[obase + 64 + lane] = f2bf(a);
        a = p2 * inv; out_attn[obase + 128 + lane] = a; abf[obase + 128 + lane] = f2bf(a);
        a = p3 * inv; out_attn[obase + 192 + lane] = a; abf[obase + 192 + lane] = f2bf(a);
    }
}

// c[b,t,h] = attn[b,t,:] @ ctxT[b][h,:]   per-b GEMM M=T N=H K=S, MFMA
__global__ __launch_bounds__(256) void k_context(const u16* __restrict__ abf,
                                                 const u16* __restrict__ ctxT,
                                                 float* __restrict__ out_c,
                                                 u16* __restrict__ cbf) {
    int lane = threadIdx.x & 63, wave = threadIdx.x >> 6;
    int tile = blockIdx.x * 4 + wave;     // 65536 tiles: b(64) x mt(16) x nt(64)
    int b = tile >> 10;
    int mt = (tile >> 6) & 15, nt = tile & 63;
    int kq = (lane >> 4) * 8;
    const u16* ap = abf + ((size_t)b * TT + mt * 16 + (lane & 15)) * SS + kq;
    const u16* bp = ctxT + ((size_t)b * HH + nt * 16 + (lane & 15)) * SS + kq;
    f32x4 acc = mfma_acc(ap, bp, SS, f32x4{0.f, 0.f, 0.f, 0.f});
    int h = nt * 16 + (lane & 15);
    int mbase = mt * 16 + (lane >> 4) * 4;
#pragma unroll
    for (int r = 0; r < 4; ++r) {
        int t = mbase + r;
        float c = acc[r];
        out_c[((size_t)b * TT + t) * HH + h] = c;       // c_out[b,t,:]
        cbf[((size_t)t * 64 + b) * HH + h] = f2bf(c);   // cbf[t][b][:]  (m = t*64+b)
    }
}

// h_tilde[m,n] = tanh([c,hy][m,:] @ Wa_out.T)  (M=16384, K=2048 split c|hy)
__global__ __launch_bounds__(256) void k_htilde(const u16* __restrict__ cbf,
                                                const u16* __restrict__ hbf,
                                                const u16* __restrict__ waoutbf,
                                                float* __restrict__ out_ht) {
    int lane = threadIdx.x & 63, wave = threadIdx.x >> 6;
    int tile = blockIdx.x * 4 + wave;    // 65536 tiles
    int mt = tile >> 6, nt = tile & 63;
    int kq = (lane >> 4) * 8;
    int m16 = mt * 16 + (lane & 15);
    int n = nt * 16 + (lane & 15);
    const u16* bp = waoutbf + (size_t)n * H2 + kq;
    f32x4 acc = mfma_acc(cbf + (size_t)m16 * HH + kq, bp, HH, f32x4{0.f, 0.f, 0.f, 0.f});
    acc = mfma_acc(hbf + (size_t)m16 * HH + kq, bp + HH, HH, acc);
    int mbase = mt * 16 + (lane >> 4) * 4;
#pragma unroll
    for (int r = 0; r < 4; ++r) {
        int mrow = mbase + r;
        int t = mrow >> 6, b = mrow & 63;
        out_ht[((size_t)b * TT + t) * HH + n] = fast_tanh(acc[r]);
    }
}

__global__ __launch_bounds__(256) void k_final(const float* __restrict__ cell,
                                               float* __restrict__ out) {
    int i = blockIdx.x * 256 + threadIdx.x;  // 65536
    int b = i >> 10, h = i & 1023;
    size_t hy_off = 3 * BTH + BTS;
    out[hy_off + i] = out[(size_t)b * TT * HH + (size_t)(TT - 1) * HH + h];
    out[hy_off + (size_t)BB * HH + i] = cell[i];
}

extern "C" void kernel_launch(void* const* d_in, const int* in_sizes, int n_in,
                              void* d_out, int out_size, void* d_ws, size_t ws_size,
                              hipStream_t stream) {
    const float* input  = (const float*)d_in[0];
    const float* hx0    = (const float*)d_in[1];
    const float* cx0    = (const float*)d_in[2];
    const float* ctx    = (const float*)d_in[3];
    const float* W_in   = (const float*)d_in[4];
    const float* b_in   = (const float*)d_in[5];
    const float* W_hid  = (const float*)d_in[6];
    const float* b_hid  = (const float*)d_in[7];
    const float* Wa_in  = (const float*)d_in[8];
    const float* Wa_c   = (const float*)d_in[9];
    const float* ba_c   = (const float*)d_in[10];
    const float* Wa_v   = (const float*)d_in[11];
    const float* Wa_out = (const float*)d_in[12];
    float* out = (float*)d_out;
    (void)in_sizes; (void)n_in; (void)out_size; (void)ws_size;

    char* w = (char*)d_ws;
    size_t off = 0;
    auto take = [&](size_t bytes) -> void* {
        void* p = w + off;
        off += (bytes + 255) & ~(size_t)255;
        return p;
    };
    // 64 MB union: inbf (early, 32 MB) / target fp32 (late, 64 MB)
    char* big    = (char*)take((size_t)BB * TT * HH * 4);
    u16* inbf    = (u16*)big;
    float* target = (float*)big;
    u16* xg      = (u16*)take((size_t)TT * BB * H4 * 2);   // 128 MB
    u16* hbf     = (u16*)take((size_t)TT * BB * HH * 2);   // 32 MB  [t][b][h]
    // 32 MB union: ctxbf (early, src_gemm A-operand) / cbf (late, [t][b][h])
    u16* ctxbf   = (u16*)take((size_t)BB * SS * HH * 2);
    u16* cbf     = ctxbf;
    u16* srcbf   = (u16*)take((size_t)BB * SS * HH * 2);   // 32 MB
    u16* ctxT    = (u16*)take((size_t)BB * SS * HH * 2);   // 32 MB  [b][h][s]
    u16* abf     = (u16*)take((size_t)BB * TT * SS * 2);   // 8 MB   [b][t][s]
    u16* winbf   = (u16*)take((size_t)H4 * II * 2);        // 8 MB
    u16* whidbf  = (u16*)take((size_t)H4 * HH * 2);        // 8 MB
    u16* wainbf  = (u16*)take((size_t)HH * HH * 2);        // 2 MB
    u16* wacbf   = (u16*)take((size_t)HH * HH * 2);        // 2 MB
    u16* waoutbf = (u16*)take((size_t)HH * H2 * 2);        // 4 MB
    u16* h0bf    = (u16*)take((size_t)BB * HH * 2);
    float* cell  = (float*)take((size_t)BB * HH * 4);

    // one-time precompute
    k_f2bf<<<(BB * TT * II) / 256, 256, 0, stream>>>(input, inbf, BB * TT * II);
    k_f2bf<<<(H4 * II) / 256, 256, 0, stream>>>(W_in, winbf, H4 * II);
    k_f2bf<<<(H4 * HH) / 256, 256, 0, stream>>>(W_hid, whidbf, H4 * HH);
    k_f2bf<<<(HH * HH) / 256, 256, 0, stream>>>(Wa_in, wainbf, HH * HH);
    k_f2bf<<<(HH * HH) / 256, 256, 0, stream>>>(Wa_c, wacbf, HH * HH);
    k_f2bf<<<(HH * H2) / 256, 256, 0, stream>>>(Wa_out, waoutbf, HH * H2);
    k_f2bf<<<(BB * SS * HH) / 256, 256, 0, stream>>>(ctx, ctxbf, BB * SS * HH);
    k_ctxT<<<16384, 256, 0, stream>>>(ctx, ctxT);
    k_src_gemm<<<16384, 256, 0, stream>>>(ctxbf, wacbf, ba_c, srcbf);
    k_xg_gemm<<<65536, 256, 0, stream>>>(inbf, winbf, b_in, xg);
    k_init<<<256, 256, 0, stream>>>(hx0, cx0, cell, h0bf);

    // phase 1: sequential LSTM (1 launch/step)
    const u16* hprev = h0bf;
    for (int t = 0; t < TT; ++t) {
        u16* hbf_t = hbf + (size_t)t * BB * HH;
        k_step<<<256, 512, 0, stream>>>(hprev, whidbf, xg + (size_t)t * BB * H4,
                                        b_hid, cell, out + (size_t)t * HH, hbf_t);
        hprev = hbf_t;
    }

    // phase 2: attention for all t in parallel
    k_target_big<<<16384, 256, 0, stream>>>(hbf, wainbf, target);
    k_attn<<<1024, 256, 0, stream>>>(target, srcbf, Wa_v, out + 3 * BTH, abf);
    k_context<<<16384, 256, 0, stream>>>(abf, ctxT, out + 2 * BTH, cbf);
    k_htilde<<<16384, 256, 0, stream>>>(cbf, hbf, waoutbf, out + BTH);
    k_final<<<256, 256, 0, stream>>>(cell, out);
}